// Round 12
// baseline (5533.780 us; speedup 1.0000x reference)
//
#include <hip/hip_runtime.h>
#include <math.h>

// Diffusion sampler: 49 sequential steps, rows independent.
// Round 12: 4 waves/SIMD via TWO 512-thread blocks per CU (8 rows each).
// VGPR facts (measured R8-R11): 512thr->128 cap, 1024thr->64 cap; distance-1
// ping-pong is the deepest pipeline that fits 128. Coverage doubles via
// occupancy instead: 512 blocks x 512 threads, wave w: cols [32w,32w+32),
// lane: 1 row x 4 cols. Weights stream 2x per CU per step (L2 has headroom).
// Summation order identical to R10 -> bitwise-same outputs.
// All f32. PRNG: JAX threefry2x32, partitionable mode.

#define DXY 288
#define HID 256
#define NTHR 512
#define XYP 296                 // xy_s stride (8 floats pad past 288)
#define HP  264                 // h_s stride (8 floats pad past 256)
#define OUT_Y_OFF 1048576
#define OUT_T_OFF 1179648
#define STEP_OFF 25600          // ws: ct at t*512; [stepf,sstep] at STEP_OFF+2t
#define WS_SWE 25728            // ws: sh_w extra cols transposed [32][256]

typedef unsigned int u32;

__device__ __forceinline__ void tf2x32(u32 k0, u32 k1, u32 x0, u32 x1, u32& o0, u32& o1) {
  u32 ks2 = k0 ^ k1 ^ 0x1BD11BDAu;
#define TFR(r) { x0 += x1; x1 = (x1 << (r)) | (x1 >> (32 - (r))); x1 ^= x0; }
  x0 += k0; x1 += k1;
  TFR(13) TFR(15) TFR(26) TFR(6)
  x0 += k1;  x1 += ks2 + 1u;
  TFR(17) TFR(29) TFR(16) TFR(24)
  x0 += ks2; x1 += k0 + 2u;
  TFR(13) TFR(15) TFR(26) TFR(6)
  x0 += k0;  x1 += k1 + 3u;
  TFR(17) TFR(29) TFR(16) TFR(24)
  x0 += k1;  x1 += ks2 + 4u;
  TFR(13) TFR(15) TFR(26) TFR(6)
  x0 += ks2; x1 += k0 + 5u;
#undef TFR
  o0 = x0; o1 = x1;
}

__device__ __forceinline__ u32 pbits(u32 ka, u32 kb, u32 j) {
  u32 w0, w1;
  tf2x32(ka, kb, 0u, j, w0, w1);
  return w0 ^ w1;
}

__device__ __forceinline__ float u01f(u32 bits) {
  union { u32 i; float f; } v;
  v.i = (bits >> 9) | 0x3F800000u;
  return v.f - 1.0f;
}

// XLA f32 ErfInv (Giles polynomial)
__device__ __forceinline__ float erfinv32(float x) {
  float w = -log1pf(-x * x);
  float p;
  if (w < 5.0f) {
    w -= 2.5f;
    p = 2.81022636e-08f;
    p = fmaf(p, w, 3.43273939e-07f);
    p = fmaf(p, w, -3.5233877e-06f);
    p = fmaf(p, w, -4.39150654e-06f);
    p = fmaf(p, w, 0.00021858087f);
    p = fmaf(p, w, -0.00125372503f);
    p = fmaf(p, w, -0.00417768164f);
    p = fmaf(p, w, 0.246640727f);
    p = fmaf(p, w, 1.50140941f);
  } else {
    w = sqrtf(w) - 3.0f;
    p = -0.000200214257f;
    p = fmaf(p, w, 0.000100950558f);
    p = fmaf(p, w, 0.00134934322f);
    p = fmaf(p, w, -0.00367342844f);
    p = fmaf(p, w, 0.00573950773f);
    p = fmaf(p, w, -0.0076224613f);
    p = fmaf(p, w, 0.00943887047f);
    p = fmaf(p, w, 1.00167406f);
    p = fmaf(p, w, 2.83297682f);
  }
  return p * x;
}

__device__ __forceinline__ float nrmf(u32 bits) {
  float val = fmaf(u01f(bits), 2.0f, -0.99999994f);
  return 1.41421356f * erfinv32(val);
}
__device__ __forceinline__ float gumf(u32 bits) {
  float u = fmaxf(u01f(bits), 1.17549435e-38f);
  return -logf(-logf(u));
}
__device__ __forceinline__ float siluf(float x) {
  return x / (1.0f + expf(-x));
}

// ---- 8k weight chunk: 8 rows x 4 cols, row-major float4 (coalesced) ----
struct B8 { float4 a0, a1, a2, a3, b0, b1, b2, b3; };

template<int LD>
__device__ __forceinline__ void loadB8(B8& B, const float* p, int kk) {
  const float* q = p + kk * LD;
  const float* q2 = q + 4 * LD;
  B.a0 = *(const float4*)(q);
  B.a1 = *(const float4*)(q + LD);
  B.a2 = *(const float4*)(q + 2 * LD);
  B.a3 = *(const float4*)(q + 3 * LD);
  B.b0 = *(const float4*)(q2);
  B.b1 = *(const float4*)(q2 + LD);
  B.b2 = *(const float4*)(q2 + 2 * LD);
  B.b3 = *(const float4*)(q2 + 3 * LD);
}

// acc[c] += sum over 8 k of x[k]*B[k][c]  (k ascending)
__device__ __forceinline__ void fma8x4(float acc[4], const float4 x0, const float4 x1, const B8& B) {
  acc[0]=fmaf(x0.x,B.a0.x,acc[0]); acc[1]=fmaf(x0.x,B.a0.y,acc[1]); acc[2]=fmaf(x0.x,B.a0.z,acc[2]); acc[3]=fmaf(x0.x,B.a0.w,acc[3]);
  acc[0]=fmaf(x0.y,B.a1.x,acc[0]); acc[1]=fmaf(x0.y,B.a1.y,acc[1]); acc[2]=fmaf(x0.y,B.a1.z,acc[2]); acc[3]=fmaf(x0.y,B.a1.w,acc[3]);
  acc[0]=fmaf(x0.z,B.a2.x,acc[0]); acc[1]=fmaf(x0.z,B.a2.y,acc[1]); acc[2]=fmaf(x0.z,B.a2.z,acc[2]); acc[3]=fmaf(x0.z,B.a2.w,acc[3]);
  acc[0]=fmaf(x0.w,B.a3.x,acc[0]); acc[1]=fmaf(x0.w,B.a3.y,acc[1]); acc[2]=fmaf(x0.w,B.a3.z,acc[2]); acc[3]=fmaf(x0.w,B.a3.w,acc[3]);
  acc[0]=fmaf(x1.x,B.b0.x,acc[0]); acc[1]=fmaf(x1.x,B.b0.y,acc[1]); acc[2]=fmaf(x1.x,B.b0.z,acc[2]); acc[3]=fmaf(x1.x,B.b0.w,acc[3]);
  acc[0]=fmaf(x1.y,B.b1.x,acc[0]); acc[1]=fmaf(x1.y,B.b1.y,acc[1]); acc[2]=fmaf(x1.y,B.b1.z,acc[2]); acc[3]=fmaf(x1.y,B.b1.w,acc[3]);
  acc[0]=fmaf(x1.z,B.b2.x,acc[0]); acc[1]=fmaf(x1.z,B.b2.y,acc[1]); acc[2]=fmaf(x1.z,B.b2.z,acc[2]); acc[3]=fmaf(x1.z,B.b2.w,acc[3]);
  acc[0]=fmaf(x1.w,B.b3.x,acc[0]); acc[1]=fmaf(x1.w,B.b3.y,acc[1]); acc[2]=fmaf(x1.w,B.b3.z,acc[2]); acc[3]=fmaf(x1.w,B.b3.w,acc[3]);
}

// 1-row x 4-col GEMM with distance-1 ping-pong prefetch. K%16==0.
// A row has >=8 floats of pad past K for the dead epilogue reads.
template<int LD, int K>
__device__ __forceinline__ void gemm1(float acc[4], const float* wp, const float* aA) {
  B8 Bp, Bq;
  float4 x0 = *(const float4*)(aA), x1 = *(const float4*)(aA + 4);
  loadB8<LD>(Bp, wp, 0);
  #pragma unroll 2
  for (int j = 0; j < K / 16; ++j) {
    const int k1 = j * 16 + 8;
    const int k2t = j * 16 + 16;
    const int k2 = (k2t < K) ? k2t : 0;          // final prefetch: dead, in-bounds
    loadB8<LD>(Bq, wp, k1);
    float4 y0 = *(const float4*)(aA + k1), y1 = *(const float4*)(aA + k1 + 4);
    fma8x4(acc, x0, x1, Bp);
    loadB8<LD>(Bp, wp, k2);
    x0 = *(const float4*)(aA + k2); x1 = *(const float4*)(aA + k2 + 4);
    fma8x4(acc, y0, y1, Bq);
  }
}

// ---- precompute: Ct[t][k][c] and step scalars into ws ----
__global__ void precompute_ct(
    const float* __restrict__ t_embed,
    const float* __restrict__ tm_w1, const float* __restrict__ tm_b1,
    const float* __restrict__ tm_w2, const float* __restrict__ tm_b2,
    const float* __restrict__ tr_w1, const float* __restrict__ tr_b1,
    float* __restrict__ ws)
{
  const int t = blockIdx.x + 1;
  const int c = threadIdx.x;
  __shared__ float tmpre[HID];
  __shared__ float tmv[HID];
  const float tau = (float)t / 50.0f;

  tmpre[c] = siluf(fmaf(tau, tm_w1[c], tm_b1[c]));
  __syncthreads();
  {
    float acc = tm_b2[c];
    for (int i = 0; i < HID; i++)
      acc = fmaf(tmpre[i], tm_w2[i * HID + c], acc);
    tmv[c] = acc;
  }
  __syncthreads();
  float D = 0.f;
  for (int i = 0; i < HID; i++)
    D = fmaf(tmv[i], tr_w1[(544 + i) * HID + c], D);
  float ce0 = tr_b1[c], ce1 = tr_b1[c];
  for (int i = 0; i < HID; i++) {
    ce0 = fmaf(t_embed[i], tr_w1[(288 + i) * HID + c], ce0);
    ce1 = fmaf(t_embed[HID + i], tr_w1[(288 + i) * HID + c], ce1);
  }
  ws[t * 512 + c] = ce0 + D;
  ws[t * 512 + 256 + c] = ce1 + D;

  if (c == 0) {
    const double lt = 6.214608098422191;  // ln 500
    float sig_t = (float)(0.002 * exp(((double)t / 50.0) * lt));
    float sig_p = (float)(0.002 * exp(((double)(t - 1) / 50.0) * lt));
    float stepf = sig_t * sig_t - sig_p * sig_p;
    ws[STEP_OFF + 2 * t] = stepf;
    ws[STEP_OFF + 2 * t + 1] = sqrtf(stepf);
  }
}

// ---- transpose sh_w extra cols into ws: wst[c][k] = sh_w[k][256+c] ----
__global__ void transpose_swe(const float* __restrict__ sw, float* __restrict__ ws)
{
  int i = blockIdx.x * 256 + threadIdx.x;   // 0..8191
  int c = i >> 8, k = i & 255;
  ws[WS_SWE + c * 256 + k] = sw[k * DXY + 256 + c];
}

// ---- main sampler: 512 blocks x 512 threads, 8 rows/block ----
__global__ __launch_bounds__(NTHR, 2) void sampler_k(
    const float* __restrict__ xy0, const int* __restrict__ t0,
    const float* __restrict__ tr_w1,
    const float* __restrict__ tr_w2, const float* __restrict__ tr_b2,
    const float* __restrict__ sh_w, const float* __restrict__ sh_b,
    const float* __restrict__ ch_w, const float* __restrict__ ch_b,
    const float* __restrict__ ws,
    float* __restrict__ out)
{
  __shared__ float xy_s[8][XYP];
  __shared__ float h1_s[8][HP];
  __shared__ float h2_s[8][HP];
  __shared__ float ct_s[2][HID];
  __shared__ int tcur_s[8];

  const int tid = threadIdx.x;
  const int lane = tid & 63;
  const int w = tid >> 6;                    // 8 waves; wave w: cols [32w, 32w+32)
  const int row0g = blockIdx.x * 8;

  const int r0 = lane >> 3;                  // row 0..7 (1 row/lane)
  const int cg = w * 32 + (lane & 7) * 4;    // 4 output cols

  // G3 extra assignment: lanes 0..31 active; row = lane>>2, col = w*4+(lane&3)
  const int rEx = (lane & 31) >> 2;
  const int cEl = w * 4 + (lane & 3);        // 0..31
  const bool exAct = (lane < 32);

  const float* w1b = tr_w1 + cg;
  const float* w2b = tr_w2 + cg;
  const float* swb = sh_w + cg;
  const float* epb = ws + WS_SWE + cEl * 256;

  // ---- prologue ----
  for (int idx = tid; idx < 8 * (DXY / 4); idx += NTHR) {
    int r = idx / (DXY / 4);
    int q = idx - r * (DXY / 4);
    *(float4*)&xy_s[r][q * 4] = *(const float4*)(xy0 + (row0g + r) * DXY + q * 4);
  }
  if (tid < 8) tcur_s[tid] = t0[row0g + tid];
  ((float*)ct_s)[tid] = ws[49 * 512 + tid];

  float chw0[4], chw1[4];                    // logits: cols lane*4..+3
  #pragma unroll
  for (int j = 0; j < 4; j++) {
    chw0[j] = ch_w[(lane * 4 + j) * 2 + 0];
    chw1[j] = ch_w[(lane * 4 + j) * 2 + 1];
  }
  const float4 b2r = *(const float4*)(tr_b2 + cg);
  const float cb0 = ch_b[0], cb1 = ch_b[1];
  const float4 sbm = *(const float4*)(sh_b + cg);
  const float sbE = sh_b[256 + cEl];
  __syncthreads();

  #pragma unroll 1
  for (int t_idx = 49; t_idx >= 1; --t_idx) {
    const float stepf = ws[STEP_OFF + 2 * t_idx];
    const float sstep = ws[STEP_OFF + 2 * t_idx + 1];

    u32 f0, f1, k1a, k1b, k2a, k2b;
    tf2x32(0u, 42u, 0u, (u32)t_idx, f0, f1);
    tf2x32(f0, f1, 0u, 0u, k1a, k1b);
    tf2x32(f0, f1, 0u, 1u, k2a, k2b);

    // ---- G1: h1 = silu(xy @ W1[0:288] + Ct[t]) ----
    {
      const int tc0 = tcur_s[r0];
      float acc[4] = {0.f, 0.f, 0.f, 0.f};
      gemm1<HID, 288>(acc, w1b, &xy_s[r0][0]);
      const float4 ct = *(const float4*)&ct_s[tc0][cg];
      float4 o;
      o.x = siluf(acc[0] + ct.x); o.y = siluf(acc[1] + ct.y);
      o.z = siluf(acc[2] + ct.z); o.w = siluf(acc[3] + ct.w);
      *(float4*)&h1_s[r0][cg] = o;
    }
    __syncthreads();   // h1 ready

    // ---- G2: h2 = silu(h1 @ W2 + b2) ----
    {
      float acc[4] = {0.f, 0.f, 0.f, 0.f};
      gemm1<HID, 256>(acc, w2b, &h1_s[r0][0]);
      float4 o;
      o.x = siluf(acc[0] + b2r.x); o.y = siluf(acc[1] + b2r.y);
      o.z = siluf(acc[2] + b2r.z); o.w = siluf(acc[3] + b2r.w);
      *(float4*)&h2_s[r0][cg] = o;
    }
    __syncthreads();   // h2 ready

    // ---- logits + categorical: wave w -> row w ----
    {
      float4 hL = *(const float4*)&h2_s[w][lane * 4];
      float p0 = hL.x * chw0[0] + hL.y * chw0[1] + hL.z * chw0[2] + hL.w * chw0[3];
      float p1 = hL.x * chw1[0] + hL.y * chw1[1] + hL.z * chw1[2] + hL.w * chw1[3];
      #pragma unroll
      for (int off = 32; off > 0; off >>= 1) {
        p0 += __shfl_xor(p0, off);
        p1 += __shfl_xor(p1, off);
      }
      float g = gumf(pbits(k2a, k2b, (u32)(row0g + w) * 2u + (u32)(lane & 1)));
      float g0 = __shfl(g, 0), g1 = __shfl(g, 1);
      if (lane == 0)
        tcur_s[w] = (p1 + cb1 + g1 > p0 + cb0 + g0) ? 1 : 0;
    }

    // ---- G3 main: score cols 0..255; xy += step*score + sqrt(step)*noise ----
    {
      float acc[4] = {0.f, 0.f, 0.f, 0.f};
      gemm1<DXY, 256>(acc, swb, &h2_s[r0][0]);
      const u32 jA = (u32)(row0g + r0) * 288u + (u32)cg;
      float4 xA = *(const float4*)&xy_s[r0][cg];
      xA.x = fmaf(sstep, nrmf(pbits(k1a, k1b, jA + 0u)), fmaf(stepf, acc[0] + sbm.x, xA.x));
      xA.y = fmaf(sstep, nrmf(pbits(k1a, k1b, jA + 1u)), fmaf(stepf, acc[1] + sbm.y, xA.y));
      xA.z = fmaf(sstep, nrmf(pbits(k1a, k1b, jA + 2u)), fmaf(stepf, acc[2] + sbm.z, xA.z));
      xA.w = fmaf(sstep, nrmf(pbits(k1a, k1b, jA + 3u)), fmaf(stepf, acc[3] + sbm.w, xA.w));
      *(float4*)&xy_s[r0][cg] = xA;
    }

    // ---- G3 extra: cols 256..287 via transposed tile (k-major float4) ----
    if (exAct) {
      float sE0 = 0.f, sE1 = 0.f;
      #pragma unroll 4
      for (int k = 0; k < 256; k += 8) {
        float4 h0  = *(const float4*)&h2_s[rEx][k];
        float4 h1v = *(const float4*)&h2_s[rEx][k + 4];
        float4 wa = *(const float4*)(epb + k);
        float4 wb = *(const float4*)(epb + k + 4);
        sE0 = fmaf(h0.w, wa.w, fmaf(h0.z, wa.z, fmaf(h0.y, wa.y, fmaf(h0.x, wa.x, sE0))));
        sE1 = fmaf(h1v.w, wb.w, fmaf(h1v.z, wb.z, fmaf(h1v.y, wb.y, fmaf(h1v.x, wb.x, sE1))));
      }
      float sE = sE0 + sE1;
      u32 jE = (u32)(row0g + rEx) * 288u + (u32)(256 + cEl);
      float nE = nrmf(pbits(k1a, k1b, jE));
      xy_s[rEx][256 + cEl] = fmaf(sstep, nE, fmaf(stepf, sE + sbE, xy_s[rEx][256 + cEl]));
    }

    // ---- stage Ct for next step ----
    if (t_idx > 1) ((float*)ct_s)[tid] = ws[(t_idx - 1) * 512 + tid];
    __syncthreads();   // xy/tcur/ct ready for next G1
  }

  // ---- final store: x (4096x256), y (4096x32), t (4096) ----
  {
    int r = tid >> 6;
    int c4 = (tid & 63) * 4;
    *(float4*)(out + (row0g + r) * 256 + c4) = *(const float4*)&xy_s[r][c4];
  }
  if (tid < 64) {
    int r = tid >> 3;
    int c4 = (tid & 7) * 4;
    *(float4*)(out + OUT_Y_OFF + (row0g + r) * 32 + c4) = *(const float4*)&xy_s[r][256 + c4];
  }
  if (tid < 8) out[OUT_T_OFF + row0g + tid] = (float)tcur_s[tid];
}

extern "C" void kernel_launch(void* const* d_in, const int* in_sizes, int n_in,
                              void* d_out, int out_size, void* d_ws, size_t ws_size,
                              hipStream_t stream) {
  (void)in_sizes; (void)n_in; (void)ws_size; (void)out_size;
  const float* xy0     = (const float*)d_in[0];
  const int*   t0      = (const int*)d_in[1];
  const float* t_embed = (const float*)d_in[2];
  const float* tm_w1   = (const float*)d_in[3];
  const float* tm_b1   = (const float*)d_in[4];
  const float* tm_w2   = (const float*)d_in[5];
  const float* tm_b2   = (const float*)d_in[6];
  const float* tr_w1   = (const float*)d_in[7];
  const float* tr_b1   = (const float*)d_in[8];
  const float* tr_w2   = (const float*)d_in[9];
  const float* tr_b2   = (const float*)d_in[10];
  const float* sh_w    = (const float*)d_in[11];
  const float* sh_b    = (const float*)d_in[12];
  const float* ch_w    = (const float*)d_in[13];
  const float* ch_b    = (const float*)d_in[14];
  float* ws  = (float*)d_ws;
  float* out = (float*)d_out;

  precompute_ct<<<49, 256, 0, stream>>>(t_embed, tm_w1, tm_b1, tm_w2, tm_b2,
                                        tr_w1, tr_b1, ws);
  transpose_swe<<<32, 256, 0, stream>>>(sh_w, ws);
  sampler_k<<<512, NTHR, 0, stream>>>(xy0, t0, tr_w1, tr_w2, tr_b2,
                                      sh_w, sh_b, ch_w, ch_b, ws, out);
}

// Round 13
// 2227.365 us; speedup vs baseline: 2.4845x; 2.4845x over previous
//
#include <hip/hip_runtime.h>
#include <math.h>

// Diffusion sampler: 49 sequential steps, rows independent.
// Round 13: LDS-staged double-buffered weight tiles (global_load_lds w16,
// counted vmcnt(4) + raw s_barrier; never vmcnt(0) in the loop).
// Evidence: R5-R12 invariant = chunks x exposed-latency; per-XCD L2 thrashes
// (27MB/step vs 4MiB) so global B-loads run at far-cache latency and the
// 128-VGPR cap (measured R11) forbids deeper pipelining. B-reads now hit LDS.
// 256 blocks x 512 threads; 16 rows/block; wave w: cols [32w,32w+32);
// lane: 2 rows x 4 cols. 25 tiles/step (9+8+8), 32KB each, 2 buffers.
// All f32. PRNG: JAX threefry2x32, partitionable. Sum order == R10 (bitwise).

#define DXY 288
#define HID 256
#define NTHR 512
#define XYP 296
#define HP  264
#define OUT_Y_OFF 1048576
#define OUT_T_OFF 1179648
#define STEP_OFF 25600          // ws: ct at t*512; [stepf,sstep] at STEP_OFF+2t
#define WS_SWE 25728            // ws: sh_w cols 256..287 transposed [32][256]

typedef unsigned int u32;

__device__ __forceinline__ void tf2x32(u32 k0, u32 k1, u32 x0, u32 x1, u32& o0, u32& o1) {
  u32 ks2 = k0 ^ k1 ^ 0x1BD11BDAu;
#define TFR(r) { x0 += x1; x1 = (x1 << (r)) | (x1 >> (32 - (r))); x1 ^= x0; }
  x0 += k0; x1 += k1;
  TFR(13) TFR(15) TFR(26) TFR(6)
  x0 += k1;  x1 += ks2 + 1u;
  TFR(17) TFR(29) TFR(16) TFR(24)
  x0 += ks2; x1 += k0 + 2u;
  TFR(13) TFR(15) TFR(26) TFR(6)
  x0 += k0;  x1 += k1 + 3u;
  TFR(17) TFR(29) TFR(16) TFR(24)
  x0 += k1;  x1 += ks2 + 4u;
  TFR(13) TFR(15) TFR(26) TFR(6)
  x0 += ks2; x1 += k0 + 5u;
#undef TFR
  o0 = x0; o1 = x1;
}

__device__ __forceinline__ u32 pbits(u32 ka, u32 kb, u32 j) {
  u32 w0, w1;
  tf2x32(ka, kb, 0u, j, w0, w1);
  return w0 ^ w1;
}

__device__ __forceinline__ float u01f(u32 bits) {
  union { u32 i; float f; } v;
  v.i = (bits >> 9) | 0x3F800000u;
  return v.f - 1.0f;
}

// XLA f32 ErfInv (Giles polynomial)
__device__ __forceinline__ float erfinv32(float x) {
  float w = -log1pf(-x * x);
  float p;
  if (w < 5.0f) {
    w -= 2.5f;
    p = 2.81022636e-08f;
    p = fmaf(p, w, 3.43273939e-07f);
    p = fmaf(p, w, -3.5233877e-06f);
    p = fmaf(p, w, -4.39150654e-06f);
    p = fmaf(p, w, 0.00021858087f);
    p = fmaf(p, w, -0.00125372503f);
    p = fmaf(p, w, -0.00417768164f);
    p = fmaf(p, w, 0.246640727f);
    p = fmaf(p, w, 1.50140941f);
  } else {
    w = sqrtf(w) - 3.0f;
    p = -0.000200214257f;
    p = fmaf(p, w, 0.000100950558f);
    p = fmaf(p, w, 0.00134934322f);
    p = fmaf(p, w, -0.00367342844f);
    p = fmaf(p, w, 0.00573950773f);
    p = fmaf(p, w, -0.0076224613f);
    p = fmaf(p, w, 0.00943887047f);
    p = fmaf(p, w, 1.00167406f);
    p = fmaf(p, w, 2.83297682f);
  }
  return p * x;
}

__device__ __forceinline__ float nrmf(u32 bits) {
  float val = fmaf(u01f(bits), 2.0f, -0.99999994f);
  return 1.41421356f * erfinv32(val);
}
__device__ __forceinline__ float gumf(u32 bits) {
  float u = fmaxf(u01f(bits), 1.17549435e-38f);
  return -logf(-logf(u));
}
__device__ __forceinline__ float siluf(float x) {
  return x / (1.0f + expf(-x));
}

struct B8 { float4 a0, a1, a2, a3, b0, b1, b2, b3; };

// acc[c] += sum over 8 k of x[k]*B[k][c]  (k ascending; identical to R10)
__device__ __forceinline__ void fma8x4(float acc[4], const float4 x0, const float4 x1, const B8& B) {
  acc[0]=fmaf(x0.x,B.a0.x,acc[0]); acc[1]=fmaf(x0.x,B.a0.y,acc[1]); acc[2]=fmaf(x0.x,B.a0.z,acc[2]); acc[3]=fmaf(x0.x,B.a0.w,acc[3]);
  acc[0]=fmaf(x0.y,B.a1.x,acc[0]); acc[1]=fmaf(x0.y,B.a1.y,acc[1]); acc[2]=fmaf(x0.y,B.a1.z,acc[2]); acc[3]=fmaf(x0.y,B.a1.w,acc[3]);
  acc[0]=fmaf(x0.z,B.a2.x,acc[0]); acc[1]=fmaf(x0.z,B.a2.y,acc[1]); acc[2]=fmaf(x0.z,B.a2.z,acc[2]); acc[3]=fmaf(x0.z,B.a2.w,acc[3]);
  acc[0]=fmaf(x0.w,B.a3.x,acc[0]); acc[1]=fmaf(x0.w,B.a3.y,acc[1]); acc[2]=fmaf(x0.w,B.a3.z,acc[2]); acc[3]=fmaf(x0.w,B.a3.w,acc[3]);
  acc[0]=fmaf(x1.x,B.b0.x,acc[0]); acc[1]=fmaf(x1.x,B.b0.y,acc[1]); acc[2]=fmaf(x1.x,B.b0.z,acc[2]); acc[3]=fmaf(x1.x,B.b0.w,acc[3]);
  acc[0]=fmaf(x1.y,B.b1.x,acc[0]); acc[1]=fmaf(x1.y,B.b1.y,acc[1]); acc[2]=fmaf(x1.y,B.b1.z,acc[2]); acc[3]=fmaf(x1.y,B.b1.w,acc[3]);
  acc[0]=fmaf(x1.z,B.b2.x,acc[0]); acc[1]=fmaf(x1.z,B.b2.y,acc[1]); acc[2]=fmaf(x1.z,B.b2.z,acc[2]); acc[3]=fmaf(x1.z,B.b2.w,acc[3]);
  acc[0]=fmaf(x1.w,B.b3.x,acc[0]); acc[1]=fmaf(x1.w,B.b3.y,acc[1]); acc[2]=fmaf(x1.w,B.b3.z,acc[2]); acc[3]=fmaf(x1.w,B.b3.w,acc[3]);
}

// async 16B global -> LDS (dest = wave-uniform base + lane*16; our per-lane
// pointers are exactly affine with slope 16B, so the pattern matches)
__device__ __forceinline__ void gll16(const float* g, float* l) {
  __builtin_amdgcn_global_load_lds((const __attribute__((address_space(1))) void*)g,
                                   (__attribute__((address_space(3))) void*)l, 16, 0, 0);
}

// stage one 32KB tile (2048 x 16B units; 4 units/thread)
__device__ __forceinline__ void issue_stage(int seq, float* buf, int tid,
                                            const float* w1, const float* w2,
                                            const float* sw) {
  if (seq < 17) {
    const float* src = (seq < 9) ? (w1 + seq * 8192) : (w2 + (seq - 9) * 8192);
    #pragma unroll
    for (int j = 0; j < 4; ++j) {
      int u = j * 512 + tid;
      gll16(src + u * 4, buf + u * 4);
    }
  } else {
    const int t0 = (seq - 17) * 32;
    #pragma unroll
    for (int j = 0; j < 4; ++j) {
      int u = j * 512 + tid;
      int r = u >> 6, c4 = (u & 63) << 2;
      gll16(sw + (t0 + r) * DXY + c4, buf + u * 4);
    }
  }
}

// one 32-k tile of the 2-row x 4-col GEMM; B from LDS tile [32][256]
__device__ __forceinline__ void tile_mm(float accA[4], float accB[4],
                                        const float* tile, const float* aA,
                                        const float* aB, int cg) {
  #pragma unroll
  for (int kk = 0; kk < 32; kk += 8) {
    const float* tp = tile + kk * 256 + cg;
    B8 B;
    B.a0 = *(const float4*)(tp);
    B.a1 = *(const float4*)(tp + 256);
    B.a2 = *(const float4*)(tp + 512);
    B.a3 = *(const float4*)(tp + 768);
    B.b0 = *(const float4*)(tp + 1024);
    B.b1 = *(const float4*)(tp + 1280);
    B.b2 = *(const float4*)(tp + 1536);
    B.b3 = *(const float4*)(tp + 1792);
    float4 xA0 = *(const float4*)(aA + kk), xA1 = *(const float4*)(aA + kk + 4);
    float4 xB0 = *(const float4*)(aB + kk), xB1 = *(const float4*)(aB + kk + 4);
    fma8x4(accA, xA0, xA1, B);
    fma8x4(accB, xB0, xB1, B);
  }
}

// tile s ready: own stage loads for tile s retired (<=4 outstanding = tile s+1's)
#define WAIT_TILE() do { \
  asm volatile("s_waitcnt vmcnt(4)" ::: "memory"); \
  __builtin_amdgcn_s_barrier(); \
  __builtin_amdgcn_sched_barrier(0); } while (0)

// all waves done computing this tile (and LDS stores flushed)
#define DONE_TILE() do { \
  asm volatile("s_waitcnt lgkmcnt(0)" ::: "memory"); \
  __builtin_amdgcn_s_barrier(); \
  __builtin_amdgcn_sched_barrier(0); } while (0)

// ---- precompute: Ct[t][k][c] and step scalars into ws ----
__global__ void precompute_ct(
    const float* __restrict__ t_embed,
    const float* __restrict__ tm_w1, const float* __restrict__ tm_b1,
    const float* __restrict__ tm_w2, const float* __restrict__ tm_b2,
    const float* __restrict__ tr_w1, const float* __restrict__ tr_b1,
    float* __restrict__ ws)
{
  const int t = blockIdx.x + 1;
  const int c = threadIdx.x;
  __shared__ float tmpre[HID];
  __shared__ float tmv[HID];
  const float tau = (float)t / 50.0f;

  tmpre[c] = siluf(fmaf(tau, tm_w1[c], tm_b1[c]));
  __syncthreads();
  {
    float acc = tm_b2[c];
    for (int i = 0; i < HID; i++)
      acc = fmaf(tmpre[i], tm_w2[i * HID + c], acc);
    tmv[c] = acc;
  }
  __syncthreads();
  float D = 0.f;
  for (int i = 0; i < HID; i++)
    D = fmaf(tmv[i], tr_w1[(544 + i) * HID + c], D);
  float ce0 = tr_b1[c], ce1 = tr_b1[c];
  for (int i = 0; i < HID; i++) {
    ce0 = fmaf(t_embed[i], tr_w1[(288 + i) * HID + c], ce0);
    ce1 = fmaf(t_embed[HID + i], tr_w1[(288 + i) * HID + c], ce1);
  }
  ws[t * 512 + c] = ce0 + D;
  ws[t * 512 + 256 + c] = ce1 + D;

  if (c == 0) {
    const double lt = 6.214608098422191;  // ln 500
    float sig_t = (float)(0.002 * exp(((double)t / 50.0) * lt));
    float sig_p = (float)(0.002 * exp(((double)(t - 1) / 50.0) * lt));
    float stepf = sig_t * sig_t - sig_p * sig_p;
    ws[STEP_OFF + 2 * t] = stepf;
    ws[STEP_OFF + 2 * t + 1] = sqrtf(stepf);
  }
}

// ---- transpose sh_w extra cols into ws: [c][k] = sh_w[k][256+c] ----
__global__ void transpose_swe(const float* __restrict__ sw, float* __restrict__ ws)
{
  int i = blockIdx.x * 256 + threadIdx.x;   // 0..8191
  int c = i >> 8, k = i & 255;
  ws[WS_SWE + c * 256 + k] = sw[k * DXY + 256 + c];
}

// ---- main sampler ----
__global__ __launch_bounds__(NTHR, 2) void sampler_k(
    const float* __restrict__ xy0, const int* __restrict__ t0,
    const float* __restrict__ tr_w1,
    const float* __restrict__ tr_w2, const float* __restrict__ tr_b2,
    const float* __restrict__ sh_w, const float* __restrict__ sh_b,
    const float* __restrict__ ch_w, const float* __restrict__ ch_b,
    const float* __restrict__ ws,
    float* __restrict__ out)
{
  __shared__ float wt[2][8192];     // 64KB: double-buffered weight tiles [32][256]
  __shared__ float wext[8192];      // 32KB: sh_w cols 256..287, [c][k] (persistent)
  __shared__ float xy_s[16][XYP];   // 18.9KB
  __shared__ float h1_s[16][HP];    // 16.9KB
  __shared__ float h2_s[16][HP];    // 16.9KB
  __shared__ int tcur_s[16];

  const int tid = threadIdx.x;
  const int lane = tid & 63;
  const int w = tid >> 6;                    // 8 waves; wave w: cols [32w, 32w+32)
  const int row0g = blockIdx.x * 16;

  const int r0 = lane >> 3;                  // rows r0, r0+8
  const int r1 = r0 + 8;
  const int cg = w * 32 + (lane & 7) * 4;    // 4 output cols
  const int rE = lane >> 2;                  // G3 extra: 16 rows x 4 cols/wave
  const int cEl = w * 4 + (lane & 3);        // extra col 0..31

  // ---- prologue: start pipeline, load state ----
  issue_stage(0, wt[0], tid, tr_w1, tr_w2, sh_w);
  issue_stage(1, wt[1], tid, tr_w1, tr_w2, sh_w);

  for (int idx = tid; idx < 16 * (DXY / 4); idx += NTHR) {
    int r = idx / (DXY / 4);
    int q = idx - r * (DXY / 4);
    *(float4*)&xy_s[r][q * 4] = *(const float4*)(xy0 + (row0g + r) * DXY + q * 4);
  }
  for (int i = tid; i < 8192; i += NTHR) wext[i] = ws[WS_SWE + i];
  if (tid < 16) tcur_s[tid] = t0[row0g + tid];

  float chw0[4], chw1[4];
  #pragma unroll
  for (int j = 0; j < 4; j++) {
    chw0[j] = ch_w[(lane * 4 + j) * 2 + 0];
    chw1[j] = ch_w[(lane * 4 + j) * 2 + 1];
  }
  const float4 b2r = *(const float4*)(tr_b2 + cg);
  const float cb0 = ch_b[0], cb1 = ch_b[1];
  const float4 sbm = *(const float4*)(sh_b + cg);
  const float sbE = sh_b[256 + cEl];
  const float* epb = wext + cEl * 256;
  __syncthreads();   // drains prologue stages (once) + state visible

  int pp = 0;        // parity: current tile lives in wt[pp]

  #pragma unroll 1
  for (int t_idx = 49; t_idx >= 1; --t_idx) {
    const float stepf = ws[STEP_OFF + 2 * t_idx];
    const float sstep = ws[STEP_OFF + 2 * t_idx + 1];

    u32 f0, f1, k1a, k1b, k2a, k2b;
    tf2x32(0u, 42u, 0u, (u32)t_idx, f0, f1);
    tf2x32(f0, f1, 0u, 0u, k1a, k1b);
    tf2x32(f0, f1, 0u, 1u, k2a, k2b);

    // ---- G1: h1 = silu(xy @ W1[0:288] + Ct[t])  (9 tiles, seq 0..8) ----
    {
      float accA[4] = {0.f, 0.f, 0.f, 0.f};
      float accB[4] = {0.f, 0.f, 0.f, 0.f};
      #pragma unroll 1
      for (int s = 0; s < 9; ++s) {
        WAIT_TILE();
        tile_mm(accA, accB, wt[pp], &xy_s[r0][s * 32], &xy_s[r1][s * 32], cg);
        if (s == 8) {
          const int tc0 = tcur_s[r0], tc1 = tcur_s[r1];
          const float* ct = ws + t_idx * 512;
          const float4 ctA = *(const float4*)(ct + tc0 * 256 + cg);
          const float4 ctB = *(const float4*)(ct + tc1 * 256 + cg);
          float4 oA, oB;
          oA.x = siluf(accA[0] + ctA.x); oA.y = siluf(accA[1] + ctA.y);
          oA.z = siluf(accA[2] + ctA.z); oA.w = siluf(accA[3] + ctA.w);
          oB.x = siluf(accB[0] + ctB.x); oB.y = siluf(accB[1] + ctB.y);
          oB.z = siluf(accB[2] + ctB.z); oB.w = siluf(accB[3] + ctB.w);
          *(float4*)&h1_s[r0][cg] = oA;
          *(float4*)&h1_s[r1][cg] = oB;
        }
        DONE_TILE();
        issue_stage(s + 2, wt[pp], tid, tr_w1, tr_w2, sh_w);
        pp ^= 1;
      }
    }

    // ---- G2: h2 = silu(h1 @ W2 + b2)  (8 tiles, seq 9..16) ----
    {
      float accA[4] = {0.f, 0.f, 0.f, 0.f};
      float accB[4] = {0.f, 0.f, 0.f, 0.f};
      #pragma unroll 1
      for (int s = 0; s < 8; ++s) {
        WAIT_TILE();
        tile_mm(accA, accB, wt[pp], &h1_s[r0][s * 32], &h1_s[r1][s * 32], cg);
        if (s == 7) {
          float4 oA, oB;
          oA.x = siluf(accA[0] + b2r.x); oA.y = siluf(accA[1] + b2r.y);
          oA.z = siluf(accA[2] + b2r.z); oA.w = siluf(accA[3] + b2r.w);
          oB.x = siluf(accB[0] + b2r.x); oB.y = siluf(accB[1] + b2r.y);
          oB.z = siluf(accB[2] + b2r.z); oB.w = siluf(accB[3] + b2r.w);
          *(float4*)&h2_s[r0][cg] = oA;
          *(float4*)&h2_s[r1][cg] = oB;
        }
        DONE_TILE();
        issue_stage(s + 11, wt[pp], tid, tr_w1, tr_w2, sh_w);
        pp ^= 1;
      }
    }

    // ---- logits + categorical for rows {2w, 2w+1} (h2 ready) ----
    {
      float4 hL0 = *(const float4*)&h2_s[2 * w][lane * 4];
      float4 hL1 = *(const float4*)&h2_s[2 * w + 1][lane * 4];
      float pA0 = hL0.x * chw0[0] + hL0.y * chw0[1] + hL0.z * chw0[2] + hL0.w * chw0[3];
      float pA1 = hL0.x * chw1[0] + hL0.y * chw1[1] + hL0.z * chw1[2] + hL0.w * chw1[3];
      float pB0 = hL1.x * chw0[0] + hL1.y * chw0[1] + hL1.z * chw0[2] + hL1.w * chw0[3];
      float pB1 = hL1.x * chw1[0] + hL1.y * chw1[1] + hL1.z * chw1[2] + hL1.w * chw1[3];
      #pragma unroll
      for (int off = 32; off > 0; off >>= 1) {
        pA0 += __shfl_xor(pA0, off);
        pA1 += __shfl_xor(pA1, off);
        pB0 += __shfl_xor(pB0, off);
        pB1 += __shfl_xor(pB1, off);
      }
      u32 grow = (u32)(row0g + 2 * w + ((lane >> 1) & 1));
      float g = gumf(pbits(k2a, k2b, grow * 2u + (u32)(lane & 1)));
      float g0 = __shfl(g, 0), g1 = __shfl(g, 1);
      float g2 = __shfl(g, 2), g3 = __shfl(g, 3);
      if (lane == 0) {
        tcur_s[2 * w]     = (pA1 + cb1 + g1 > pA0 + cb0 + g0) ? 1 : 0;
        tcur_s[2 * w + 1] = (pB1 + cb1 + g3 > pB0 + cb0 + g2) ? 1 : 0;
      }
    }

    // ---- G3: score = h2 @ sh_w; xy update  (8 tiles, seq 17..24) ----
    {
      float accA[4] = {0.f, 0.f, 0.f, 0.f};
      float accB[4] = {0.f, 0.f, 0.f, 0.f};
      #pragma unroll 1
      for (int s = 0; s < 8; ++s) {
        WAIT_TILE();
        tile_mm(accA, accB, wt[pp], &h2_s[r0][s * 32], &h2_s[r1][s * 32], cg);
        if (s == 7) {
          // main cols
          const u32 jA = (u32)(row0g + r0) * 288u + (u32)cg;
          const u32 jB = (u32)(row0g + r1) * 288u + (u32)cg;
          float4 xA = *(const float4*)&xy_s[r0][cg];
          float4 xB = *(const float4*)&xy_s[r1][cg];
          xA.x = fmaf(sstep, nrmf(pbits(k1a, k1b, jA + 0u)), fmaf(stepf, accA[0] + sbm.x, xA.x));
          xA.y = fmaf(sstep, nrmf(pbits(k1a, k1b, jA + 1u)), fmaf(stepf, accA[1] + sbm.y, xA.y));
          xA.z = fmaf(sstep, nrmf(pbits(k1a, k1b, jA + 2u)), fmaf(stepf, accA[2] + sbm.z, xA.z));
          xA.w = fmaf(sstep, nrmf(pbits(k1a, k1b, jA + 3u)), fmaf(stepf, accA[3] + sbm.w, xA.w));
          xB.x = fmaf(sstep, nrmf(pbits(k1a, k1b, jB + 0u)), fmaf(stepf, accB[0] + sbm.x, xB.x));
          xB.y = fmaf(sstep, nrmf(pbits(k1a, k1b, jB + 1u)), fmaf(stepf, accB[1] + sbm.y, xB.y));
          xB.z = fmaf(sstep, nrmf(pbits(k1a, k1b, jB + 2u)), fmaf(stepf, accB[2] + sbm.z, xB.z));
          xB.w = fmaf(sstep, nrmf(pbits(k1a, k1b, jB + 3u)), fmaf(stepf, accB[3] + sbm.w, xB.w));
          *(float4*)&xy_s[r0][cg] = xA;
          *(float4*)&xy_s[r1][cg] = xB;
          // extra cols 256..287 from persistent LDS wext
          float sE0 = 0.f, sE1 = 0.f;
          #pragma unroll 4
          for (int k = 0; k < 256; k += 8) {
            float4 h0  = *(const float4*)&h2_s[rE][k];
            float4 h1v = *(const float4*)&h2_s[rE][k + 4];
            float4 wa = *(const float4*)(epb + k);
            float4 wb = *(const float4*)(epb + k + 4);
            sE0 = fmaf(h0.w, wa.w, fmaf(h0.z, wa.z, fmaf(h0.y, wa.y, fmaf(h0.x, wa.x, sE0))));
            sE1 = fmaf(h1v.w, wb.w, fmaf(h1v.z, wb.z, fmaf(h1v.y, wb.y, fmaf(h1v.x, wb.x, sE1))));
          }
          float sE = sE0 + sE1;
          u32 jE = (u32)(row0g + rE) * 288u + (u32)(256 + cEl);
          float nE = nrmf(pbits(k1a, k1b, jE));
          xy_s[rE][256 + cEl] = fmaf(sstep, nE, fmaf(stepf, sE + sbE, xy_s[rE][256 + cEl]));
        }
        DONE_TILE();
        int nxt = s + 19;
        if (nxt >= 25) nxt -= 25;   // wraps to next step's W1 tiles (same weights)
        issue_stage(nxt, wt[pp], tid, tr_w1, tr_w2, sh_w);
        pp ^= 1;
      }
    }
  }

  // ---- final store: x (4096x256), y (4096x32), t (4096) ----
  for (int idx = tid; idx < 16 * 64; idx += NTHR) {
    int r = idx >> 6;
    int c4 = (idx & 63) * 4;
    *(float4*)(out + (row0g + r) * 256 + c4) = *(const float4*)&xy_s[r][c4];
  }
  for (int idx = tid; idx < 16 * 8; idx += NTHR) {
    int r = idx >> 3;
    int c4 = (idx & 7) * 4;
    *(float4*)(out + OUT_Y_OFF + (row0g + r) * 32 + c4) = *(const float4*)&xy_s[r][256 + c4];
  }
  if (tid < 16) out[OUT_T_OFF + row0g + tid] = (float)tcur_s[tid];
}

extern "C" void kernel_launch(void* const* d_in, const int* in_sizes, int n_in,
                              void* d_out, int out_size, void* d_ws, size_t ws_size,
                              hipStream_t stream) {
  (void)in_sizes; (void)n_in; (void)ws_size; (void)out_size;
  const float* xy0     = (const float*)d_in[0];
  const int*   t0      = (const int*)d_in[1];
  const float* t_embed = (const float*)d_in[2];
  const float* tm_w1   = (const float*)d_in[3];
  const float* tm_b1   = (const float*)d_in[4];
  const float* tm_w2   = (const float*)d_in[5];
  const float* tm_b2   = (const float*)d_in[6];
  const float* tr_w1   = (const float*)d_in[7];
  const float* tr_b1   = (const float*)d_in[8];
  const float* tr_w2   = (const float*)d_in[9];
  const float* tr_b2   = (const float*)d_in[10];
  const float* sh_w    = (const float*)d_in[11];
  const float* sh_b    = (const float*)d_in[12];
  const float* ch_w    = (const float*)d_in[13];
  const float* ch_b    = (const float*)d_in[14];
  float* ws  = (float*)d_ws;
  float* out = (float*)d_out;

  precompute_ct<<<49, 256, 0, stream>>>(t_embed, tm_w1, tm_b1, tm_w2, tm_b2,
                                        tr_w1, tr_b1, ws);
  transpose_swe<<<32, 256, 0, stream>>>(sh_w, ws);
  sampler_k<<<256, NTHR, 0, stream>>>(xy0, t0, tr_w1, tr_w2, tr_b2,
                                      sh_w, sh_b, ch_w, ch_b, ws, out);
}